// Round 6
// baseline (301.058 us; speedup 1.0000x reference)
//
#include <hip/hip_runtime.h>
#include <math.h>

// Sizes fixed by the problem.
#define N_AG   512
#define HIDD   256
#define OBSD   128
// P = 512*511/2 = 130816 pairs, out = [P,3]

__device__ __forceinline__ void fma4(float4& acc, float4 a, float4 b){
    acc.x += a.x*b.x; acc.y += a.y*b.y; acc.z += a.z*b.z; acc.w += a.w*b.w;
}
__device__ __forceinline__ float hsum(float4 a){ return (a.x+a.y)+(a.z+a.w); }

// ---- shared GEMM-tile helpers: 64x64 output tile, K-chunks of 32, LDS [32][68] kk-major ----
__device__ __forceinline__ void stage_rows(float* dst, const float* __restrict__ src,
        int row0, int stride, int colbase, int t){
    #pragma unroll
    for (int half = 0; half < 2; ++half){
        int idx = half*256 + t;
        int row = idx >> 3, c4 = idx & 7;
        float4 v = *(const float4*)(src + (row0+row)*stride + colbase + c4*4);
        dst[(c4*4+0)*68 + row] = v.x;
        dst[(c4*4+1)*68 + row] = v.y;
        dst[(c4*4+2)*68 + row] = v.z;
        dst[(c4*4+3)*68 + row] = v.w;
    }
}
__device__ __forceinline__ void tile_compute(const float* As, const float* Bs,
        int tx, int ty, float4 acc[4]){
    #pragma unroll
    for (int kk = 0; kk < 32; ++kk){
        float4 a = *(const float4*)(As + kk*68 + ty*4);
        float4 b = *(const float4*)(Bs + kk*68 + tx*4);
        acc[0].x += a.x*b.x; acc[0].y += a.x*b.y; acc[0].z += a.x*b.z; acc[0].w += a.x*b.w;
        acc[1].x += a.y*b.x; acc[1].y += a.y*b.y; acc[1].z += a.y*b.z; acc[1].w += a.y*b.w;
        acc[2].x += a.z*b.x; acc[2].y += a.z*b.y; acc[2].z += a.z*b.z; acc[2].w += a.z*b.w;
        acc[3].x += a.w*b.x; acc[3].y += a.w*b.y; acc[3].z += a.w*b.z; acc[3].w += a.w*b.w;
    }
}

// ---------------- K1: hid = relu(inputs @ fc1_w.T + fc1_b) ----------------
__global__ __launch_bounds__(256, 2) void k_fc1(const float* __restrict__ in,
        const float* __restrict__ w, const float* __restrict__ b,
        float* __restrict__ hid){
    __shared__ float lin[8*OBSD];
    int at = blockIdx.y, ot = blockIdx.x, t = threadIdx.x;
    ((float4*)lin)[t] = ((const float4*)(in + at*8*OBSD))[t];
    __syncthreads();
    int ol = t & 63, g = t >> 6;
    int o = ot*64 + ol;
    const float4* w4 = (const float4*)(w + o*OBSD);
    const float4* la = (const float4*)(lin + (g*2)*OBSD);
    const float4* lb = (const float4*)(lin + (g*2+1)*OBSD);
    float4 a0 = {0,0,0,0}, a1 = {0,0,0,0};
    #pragma unroll
    for (int c = 0; c < OBSD/4; ++c){
        float4 wv = w4[c];
        fma4(a0, la[c], wv);
        fma4(a1, lb[c], wv);
    }
    float bb = b[o];
    int ag = at*8 + g*2;
    hid[ag*HIDD + o]     = fmaxf(hsum(a0) + bb, 0.f);
    hid[(ag+1)*HIDD + o] = fmaxf(hsum(a1) + bb, 0.f);
}

// ---------------- K2: qkv = hid @ in_proj_w.T + in_proj_b ----------------
__global__ __launch_bounds__(256, 2) void k_qkv(const float* __restrict__ hid,
        const float* __restrict__ w, const float* __restrict__ b,
        float* __restrict__ qkv){
    __shared__ float lin[8*HIDD];
    int at = blockIdx.y, ot = blockIdx.x, t = threadIdx.x;
    const float4* in4 = (const float4*)(hid + at*8*HIDD);
    ((float4*)lin)[t]       = in4[t];
    ((float4*)lin)[t + 256] = in4[t + 256];
    __syncthreads();
    int ol = t & 63, g = t >> 6;
    int o = ot*64 + ol;                       // 0..767
    const float4* w4 = (const float4*)(w + o*HIDD);
    const float4* la = (const float4*)(lin + (g*2)*HIDD);
    const float4* lb = (const float4*)(lin + (g*2+1)*HIDD);
    float4 a0 = {0,0,0,0}, a1 = {0,0,0,0};
    #pragma unroll 8
    for (int c = 0; c < HIDD/4; ++c){
        float4 wv = w4[c];
        fma4(a0, la[c], wv);
        fma4(a1, lb[c], wv);
    }
    float bb = b[o];
    int ag = at*8 + g*2;
    qkv[ag*768 + o]     = hsum(a0) + bb;
    qkv[(ag+1)*768 + o] = hsum(a1) + bb;
}

// ---------------- K3: blocks 0..63 scores S=QK^T/16 | 64..95 VW=V@ow^T | 96..2143 vfc2_w stream ----------------
// vpart restructured: 4 weight rows per block x 1 shared hid chunk (16KB) -> 164 MB total traffic,
// ~20 independent loads in flight per thread. No min-occupancy bound: let VGPRs grow.
__global__ __launch_bounds__(256) void k_big(const float* __restrict__ qkv,
        const float* __restrict__ ow, const float* __restrict__ hid,
        const float* __restrict__ vw_w, float* __restrict__ S,
        float* __restrict__ VW, float* __restrict__ partial){
    __shared__ float As[32*68];
    __shared__ float Bs[32*68];
    int t = threadIdx.x;
    int bid = blockIdx.x;
    if (bid < 64){
        // ---- scores tile: S[i0+..64][j0+..64] = dot(Q_i, K_j) * 0.0625 ----
        int ti = bid >> 3, tj = bid & 7;
        int i0 = ti*64, j0 = tj*64;
        int tx = t & 15, ty = t >> 4;
        float4 acc[4] = {{0,0,0,0},{0,0,0,0},{0,0,0,0},{0,0,0,0}};
        for (int k0 = 0; k0 < 256; k0 += 32){
            __syncthreads();
            stage_rows(As, qkv, i0, 768, k0,       t);   // Q chunk
            stage_rows(Bs, qkv, j0, 768, 256 + k0, t);   // K chunk
            __syncthreads();
            tile_compute(As, Bs, tx, ty, acc);
        }
        #pragma unroll
        for (int r = 0; r < 4; ++r){
            float4 o;
            o.x = acc[r].x*0.0625f; o.y = acc[r].y*0.0625f;
            o.z = acc[r].z*0.0625f; o.w = acc[r].w*0.0625f;
            *(float4*)(S + (i0+ty*4+r)*512 + j0 + tx*4) = o;
        }
        return;
    }
    if (bid < 96){
        // ---- VW tile: VW[j0+..64][d0+..64] = dot(V_j, ow_d) ----
        int b2 = bid - 64;
        int ti = b2 >> 2, tj = b2 & 3;
        int j0 = ti*64, d0 = tj*64;
        int tx = t & 15, ty = t >> 4;
        float4 acc[4] = {{0,0,0,0},{0,0,0,0},{0,0,0,0},{0,0,0,0}};
        for (int k0 = 0; k0 < 256; k0 += 32){
            __syncthreads();
            stage_rows(As, qkv, j0, 768, 512 + k0, t);   // V chunk
            stage_rows(Bs, ow,  d0, 256, k0,       t);   // ow chunk
            __syncthreads();
            tile_compute(As, Bs, tx, ty, acc);
        }
        #pragma unroll
        for (int r = 0; r < 4; ++r)
            *(float4*)(VW + (j0+ty*4+r)*256 + d0 + tx*4) = acc[r];
        return;
    }
    // ---- vpart: row-group g (4 rows), chunk of 4096 floats; h chunk shared across the 4 rows ----
    int id = bid - 96;                 // 0..2047
    int chunk = id & 31, g = id >> 5;  // chunk 0..31, row-group 0..63
    const float4* h4 = (const float4*)hid;
    const float4* w4 = (const float4*)vw_w;
    int cbase = chunk*1024;            // float4 units within the 32768-float4 row
    float4 hv[4];
    #pragma unroll
    for (int k = 0; k < 4; ++k) hv[k] = h4[cbase + k*256 + t];
    float acc[4];
    #pragma unroll
    for (int r = 0; r < 4; ++r){
        long rb = (long)(g*4+r)*32768 + cbase;
        float4 a = {0,0,0,0};
        #pragma unroll
        for (int k = 0; k < 4; ++k) fma4(a, hv[k], w4[rb + k*256 + t]);
        acc[r] = hsum(a);
    }
    #pragma unroll
    for (int r = 0; r < 4; ++r)
        for (int off = 32; off; off >>= 1) acc[r] += __shfl_xor(acc[r], off);
    int lane = t & 63, wid = t >> 6;
    if (lane == 0){
        As[wid*4+0] = acc[0]; As[wid*4+1] = acc[1];
        As[wid*4+2] = acc[2]; As[wid*4+3] = acc[3];
    }
    __syncthreads();
    if (t < 4){   // t = r
        float s = As[0*4+t] + As[1*4+t] + As[2*4+t] + As[3*4+t];
        partial[(g*4+t)*32 + chunk] = s;
    }
}

// ---------------- K4: row softmax in-place on S, wave per row, grid 128 ----------------
__global__ __launch_bounds__(256, 2) void k_softmax(float* __restrict__ S){
    int t = threadIdx.x, w = t >> 6, ln = t & 63;
    float* row = S + (blockIdx.x*4 + w)*512;
    float v[8];
    float m = -1e30f;
    #pragma unroll
    for (int k = 0; k < 8; ++k){ v[k] = row[ln + k*64]; m = fmaxf(m, v[k]); }
    for (int off = 32; off; off >>= 1) m = fmaxf(m, __shfl_xor(m, off));
    float s = 0.f;
    #pragma unroll
    for (int k = 0; k < 8; ++k){ v[k] = expf(v[k] - m); s += v[k]; }
    for (int off = 32; off; off >>= 1) s += __shfl_xor(s, off);
    float inv = 1.f / s;
    #pragma unroll
    for (int k = 0; k < 8; ++k) row[ln + k*64] = v[k]*inv;
}

// ---------------- K5: h = P @ VW + ob, grid 32 (8 i-tiles x 4 d-tiles) ----------------
__global__ __launch_bounds__(256, 2) void k_h(const float* __restrict__ P,
        const float* __restrict__ VW, const float* __restrict__ ob,
        float* __restrict__ hout){
    __shared__ float As[32*68];
    __shared__ float Bs[32*68];
    int bid = blockIdx.x;
    int ti = bid >> 2, tj = bid & 3;
    int i0 = ti*64, d0 = tj*64;
    int t = threadIdx.x, tx = t & 15, ty = t >> 4;
    float4 acc[4] = {{0,0,0,0},{0,0,0,0},{0,0,0,0},{0,0,0,0}};
    for (int k0 = 0; k0 < 512; k0 += 32){
        __syncthreads();
        stage_rows(As, P, i0, 512, k0, t);               // P chunk (transposed)
        #pragma unroll
        for (int half = 0; half < 2; ++half){
            int idx = half*256 + t;
            int kkr = idx >> 4, c4 = idx & 15;
            *(float4*)(Bs + kkr*68 + c4*4) = *(const float4*)(VW + (k0+kkr)*256 + d0 + c4*4);
        }
        __syncthreads();
        tile_compute(As, Bs, tx, ty, acc);
    }
    float4 bb = *(const float4*)(ob + d0 + tx*4);
    #pragma unroll
    for (int r = 0; r < 4; ++r){
        float4 o;
        o.x = acc[r].x + bb.x; o.y = acc[r].y + bb.y;
        o.z = acc[r].z + bb.z; o.w = acc[r].w + bb.w;
        *(float4*)(hout + (i0+ty*4+r)*256 + d0 + tx*4) = o;
    }
}

// ---------------- K6: A/B projections (blocks 0..511) || value finish (block 512) ----------------
__global__ __launch_bounds__(256, 2) void k_ab_value(const float* __restrict__ hin,
        const float* __restrict__ w2, const float* __restrict__ b2,
        const float* __restrict__ partial, const float* __restrict__ vb,
        const float* __restrict__ v3w, const float* __restrict__ v3b,
        float* __restrict__ A, float* __restrict__ B, float* __restrict__ value){
    int t = threadIdx.x;
    if (blockIdx.x == 512){
        float s = vb[t];
        #pragma unroll 8
        for (int c = 0; c < 32; ++c) s += partial[t*32 + c];
        s = fmaxf(s, 0.f) * v3w[t];
        for (int off = 32; off; off >>= 1) s += __shfl_xor(s, off);
        __shared__ float redv[4];
        int lane = t & 63, wid = t >> 6;
        if (lane == 0) redv[wid] = s;
        __syncthreads();
        if (t == 0) value[0] = redv[0]+redv[1]+redv[2]+redv[3] + v3b[0];
        return;
    }
    __shared__ float lin[8*HIDD];
    int id = blockIdx.x, at = id >> 3, ot = id & 7;
    const float4* in4 = (const float4*)(hin + at*8*HIDD);
    ((float4*)lin)[t]       = in4[t];
    ((float4*)lin)[t + 256] = in4[t + 256];
    __syncthreads();
    int ol = t & 63, g = t >> 6;
    int o2 = ot*64 + ol;                   // 0..511
    bool isA = o2 < HIDD;
    int o = isA ? o2 : o2 - HIDD;
    const float4* w4 = (const float4*)(w2 + o*512 + (isA ? 0 : HIDD));
    const float4* la = (const float4*)(lin + (g*2)*HIDD);
    const float4* lb = (const float4*)(lin + (g*2+1)*HIDD);
    float4 acc0 = {0,0,0,0}, acc1 = {0,0,0,0};
    #pragma unroll 8
    for (int c = 0; c < HIDD/4; ++c){
        float4 wv = w4[c];
        fma4(acc0, la[c], wv);
        fma4(acc1, lb[c], wv);
    }
    int a0 = at*8 + g*2;
    float* dst = isA ? A : B;
    float bb = isA ? b2[o] : 0.f;          // fold fc2_b into A
    dst[a0*HIDD + o]     = hsum(acc0) + bb;
    dst[(a0+1)*HIDD + o] = hsum(acc1) + bb;
}

// ---------------- K7: per-pair x=relu(A[i]+B[j]); out = [sigmoid(wd.x+bd), 1-., value] ----------------
__global__ __launch_bounds__(256, 2) void k_pairs(const float* __restrict__ A,
        const float* __restrict__ B, const float* __restrict__ w3,
        const float* __restrict__ b3, const float* __restrict__ value,
        float* __restrict__ out){
    int ti = blockIdx.x, tj = blockIdx.y;
    if (tj < ti) return;                   // strictly-lower tiles have no pairs
    __shared__ float la[16*260], lb[16*260], lw[256];
    int t = threadIdx.x;
    #pragma unroll
    for (int l = 0; l < 4; ++l){
        int idx = l*256 + t;
        int r = idx >> 6, c4 = idx & 63;
        ((float4*)la)[r*65 + c4] = ((const float4*)A)[(ti*16 + r)*64 + c4];
        ((float4*)lb)[r*65 + c4] = ((const float4*)B)[(tj*16 + r)*64 + c4];
    }
    lw[t] = w3[t] - w3[256 + t];           // fc3_w[0]-fc3_w[1]
    __syncthreads();
    float val = value[0];
    float bd  = b3[0] - b3[1];
    int il = t >> 4, jl = t & 15;
    int i = ti*16 + il, j = tj*16 + jl;
    if (j > i){
        const float4* a4 = (const float4*)(la + il*260);
        const float4* b4 = (const float4*)(lb + jl*260);
        const float4* w4 = (const float4*)lw;
        float4 acc = {0,0,0,0};
        #pragma unroll 8
        for (int c = 0; c < 64; ++c){
            float4 aa = a4[c], bb = b4[c], wv = w4[c];
            acc.x += fmaxf(aa.x + bb.x, 0.f)*wv.x;
            acc.y += fmaxf(aa.y + bb.y, 0.f)*wv.y;
            acc.z += fmaxf(aa.z + bb.z, 0.f)*wv.z;
            acc.w += fmaxf(aa.w + bb.w, 0.f)*wv.w;
        }
        float z = hsum(acc) + bd;
        float o0 = 1.f/(1.f + expf(-z));
        int p = i*511 - (i*(i-1))/2 + (j - i - 1);
        out[3*p]   = o0;
        out[3*p+1] = 1.f - o0;
        out[3*p+2] = val;
    }
}

extern "C" void kernel_launch(void* const* d_in, const int* in_sizes, int n_in,
                              void* d_out, int out_size, void* d_ws, size_t ws_size,
                              hipStream_t stream){
    const float* inputs = (const float*)d_in[0];
    const float* fc1_w  = (const float*)d_in[1];
    const float* fc1_b  = (const float*)d_in[2];
    const float* inp_w  = (const float*)d_in[3];
    const float* inp_b  = (const float*)d_in[4];
    const float* outp_w = (const float*)d_in[5];
    const float* outp_b = (const float*)d_in[6];
    const float* fc2_w  = (const float*)d_in[7];
    const float* fc2_b  = (const float*)d_in[8];
    const float* fc3_w  = (const float*)d_in[9];
    const float* fc3_b  = (const float*)d_in[10];
    const float* vfc2_w = (const float*)d_in[11];
    const float* vfc2_b = (const float*)d_in[12];
    const float* vfc3_w = (const float*)d_in[13];
    const float* vfc3_b = (const float*)d_in[14];
    float* out = (float*)d_out;
    float* ws  = (float*)d_ws;
    // ws layout (floats)
    float* hid     = ws;              // 512*256   = 131072
    float* qkv     = ws + 131072;     // 512*768   = 393216
    float* S       = ws + 524288;     // 512*512   = 262144  (scores -> softmax in place)
    float* VW      = ws + 786432;     // 512*256   = 131072
    float* h       = ws + 917504;     // 512*256   = 131072
    float* A       = ws + 1048576;    // 512*256   = 131072
    float* B       = ws + 1179648;    // 512*256   = 131072
    float* partial = ws + 1310720;    // 256*32    = 8192
    float* value   = ws + 1318912;    // 1

    k_fc1     <<<dim3(4, 64),  256, 0, stream>>>(inputs, fc1_w, fc1_b, hid);
    k_qkv     <<<dim3(12, 64), 256, 0, stream>>>(hid, inp_w, inp_b, qkv);
    k_big     <<<dim3(2144),   256, 0, stream>>>(qkv, outp_w, hid, vfc2_w, S, VW, partial);
    k_softmax <<<dim3(128),    256, 0, stream>>>(S);
    k_h       <<<dim3(32),     256, 0, stream>>>(S, VW, outp_b, h);
    k_ab_value<<<dim3(513),    256, 0, stream>>>(h, fc2_w, fc2_b, partial, vfc2_b, vfc3_w, vfc3_b, A, B, value);
    k_pairs   <<<dim3(32, 32), 256, 0, stream>>>(A, B, fc3_w, fc3_b, value, out);
}

// Round 7
// 299.460 us; speedup vs baseline: 1.0053x; 1.0053x over previous
//
#include <hip/hip_runtime.h>
#include <math.h>

// Sizes fixed by the problem.
#define N_AG   512
#define HIDD   256
#define OBSD   128
// P = 512*511/2 = 130816 pairs, out = [P,3]

__device__ __forceinline__ void fma4(float4& acc, float4 a, float4 b){
    acc.x += a.x*b.x; acc.y += a.y*b.y; acc.z += a.z*b.z; acc.w += a.w*b.w;
}
__device__ __forceinline__ float hsum(float4 a){ return (a.x+a.y)+(a.z+a.w); }

// ---- shared GEMM-tile helpers: 64x64 output tile, K-chunks of 32, LDS [32][68] kk-major ----
__device__ __forceinline__ void stage_rows(float* dst, const float* __restrict__ src,
        int row0, int stride, int colbase, int t){
    #pragma unroll
    for (int half = 0; half < 2; ++half){
        int idx = half*256 + t;
        int row = idx >> 3, c4 = idx & 7;
        float4 v = *(const float4*)(src + (row0+row)*stride + colbase + c4*4);
        dst[(c4*4+0)*68 + row] = v.x;
        dst[(c4*4+1)*68 + row] = v.y;
        dst[(c4*4+2)*68 + row] = v.z;
        dst[(c4*4+3)*68 + row] = v.w;
    }
}
__device__ __forceinline__ void tile_compute(const float* As, const float* Bs,
        int tx, int ty, float4 acc[4]){
    #pragma unroll
    for (int kk = 0; kk < 32; ++kk){
        float4 a = *(const float4*)(As + kk*68 + ty*4);
        float4 b = *(const float4*)(Bs + kk*68 + tx*4);
        acc[0].x += a.x*b.x; acc[0].y += a.x*b.y; acc[0].z += a.x*b.z; acc[0].w += a.x*b.w;
        acc[1].x += a.y*b.x; acc[1].y += a.y*b.y; acc[1].z += a.y*b.z; acc[1].w += a.y*b.w;
        acc[2].x += a.z*b.x; acc[2].y += a.z*b.y; acc[2].z += a.z*b.z; acc[2].w += a.z*b.w;
        acc[3].x += a.w*b.x; acc[3].y += a.w*b.y; acc[3].z += a.w*b.z; acc[3].w += a.w*b.w;
    }
}

// ---------------- K1: hid = relu(inputs @ fc1_w.T + fc1_b) ----------------
__global__ __launch_bounds__(256, 2) void k_fc1(const float* __restrict__ in,
        const float* __restrict__ w, const float* __restrict__ b,
        float* __restrict__ hid){
    __shared__ float lin[8*OBSD];
    int at = blockIdx.y, ot = blockIdx.x, t = threadIdx.x;
    ((float4*)lin)[t] = ((const float4*)(in + at*8*OBSD))[t];
    __syncthreads();
    int ol = t & 63, g = t >> 6;
    int o = ot*64 + ol;
    const float4* w4 = (const float4*)(w + o*OBSD);
    const float4* la = (const float4*)(lin + (g*2)*OBSD);
    const float4* lb = (const float4*)(lin + (g*2+1)*OBSD);
    float4 a0 = {0,0,0,0}, a1 = {0,0,0,0};
    #pragma unroll
    for (int c = 0; c < OBSD/4; ++c){
        float4 wv = w4[c];
        fma4(a0, la[c], wv);
        fma4(a1, lb[c], wv);
    }
    float bb = b[o];
    int ag = at*8 + g*2;
    hid[ag*HIDD + o]     = fmaxf(hsum(a0) + bb, 0.f);
    hid[(ag+1)*HIDD + o] = fmaxf(hsum(a1) + bb, 0.f);
}

// ---------------- K2: qkv = hid @ in_proj_w.T + in_proj_b ----------------
__global__ __launch_bounds__(256, 2) void k_qkv(const float* __restrict__ hid,
        const float* __restrict__ w, const float* __restrict__ b,
        float* __restrict__ qkv){
    __shared__ float lin[8*HIDD];
    int at = blockIdx.y, ot = blockIdx.x, t = threadIdx.x;
    const float4* in4 = (const float4*)(hid + at*8*HIDD);
    ((float4*)lin)[t]       = in4[t];
    ((float4*)lin)[t + 256] = in4[t + 256];
    __syncthreads();
    int ol = t & 63, g = t >> 6;
    int o = ot*64 + ol;                       // 0..767
    const float4* w4 = (const float4*)(w + o*HIDD);
    const float4* la = (const float4*)(lin + (g*2)*HIDD);
    const float4* lb = (const float4*)(lin + (g*2+1)*HIDD);
    float4 a0 = {0,0,0,0}, a1 = {0,0,0,0};
    #pragma unroll 8
    for (int c = 0; c < HIDD/4; ++c){
        float4 wv = w4[c];
        fma4(a0, la[c], wv);
        fma4(a1, lb[c], wv);
    }
    float bb = b[o];
    int ag = at*8 + g*2;
    qkv[ag*768 + o]     = hsum(a0) + bb;
    qkv[(ag+1)*768 + o] = hsum(a1) + bb;
}

// ---------------- K3: blocks 0..63 scores S=QK^T/16 | 64..95 VW=V@ow^T | 96..2143 vfc2_w stream ----------------
// vpart branch is now a PURE STREAM: loads + fma + per-thread hsum + 4 coalesced stores.
// No shuffles / LDS / barrier in the hot path (theory: reduce tail was draining the load pipe).
__global__ __launch_bounds__(256) void k_big(const float* __restrict__ qkv,
        const float* __restrict__ ow, const float* __restrict__ hid,
        const float* __restrict__ vw_w, float* __restrict__ S,
        float* __restrict__ VW, float* __restrict__ partial){
    __shared__ float As[32*68];
    __shared__ float Bs[32*68];
    int t = threadIdx.x;
    int bid = blockIdx.x;
    if (bid < 64){
        // ---- scores tile: S[i0+..64][j0+..64] = dot(Q_i, K_j) * 0.0625 ----
        int ti = bid >> 3, tj = bid & 7;
        int i0 = ti*64, j0 = tj*64;
        int tx = t & 15, ty = t >> 4;
        float4 acc[4] = {{0,0,0,0},{0,0,0,0},{0,0,0,0},{0,0,0,0}};
        for (int k0 = 0; k0 < 256; k0 += 32){
            __syncthreads();
            stage_rows(As, qkv, i0, 768, k0,       t);   // Q chunk
            stage_rows(Bs, qkv, j0, 768, 256 + k0, t);   // K chunk
            __syncthreads();
            tile_compute(As, Bs, tx, ty, acc);
        }
        #pragma unroll
        for (int r = 0; r < 4; ++r){
            float4 o;
            o.x = acc[r].x*0.0625f; o.y = acc[r].y*0.0625f;
            o.z = acc[r].z*0.0625f; o.w = acc[r].w*0.0625f;
            *(float4*)(S + (i0+ty*4+r)*512 + j0 + tx*4) = o;
        }
        return;
    }
    if (bid < 96){
        // ---- VW tile: VW[j0+..64][d0+..64] = dot(V_j, ow_d) ----
        int b2 = bid - 64;
        int ti = b2 >> 2, tj = b2 & 3;
        int j0 = ti*64, d0 = tj*64;
        int tx = t & 15, ty = t >> 4;
        float4 acc[4] = {{0,0,0,0},{0,0,0,0},{0,0,0,0},{0,0,0,0}};
        for (int k0 = 0; k0 < 256; k0 += 32){
            __syncthreads();
            stage_rows(As, qkv, j0, 768, 512 + k0, t);   // V chunk
            stage_rows(Bs, ow,  d0, 256, k0,       t);   // ow chunk
            __syncthreads();
            tile_compute(As, Bs, tx, ty, acc);
        }
        #pragma unroll
        for (int r = 0; r < 4; ++r)
            *(float4*)(VW + (j0+ty*4+r)*256 + d0 + tx*4) = acc[r];
        return;
    }
    // ---- vpart: row-group g (4 rows) x chunk of 4096 floats; h chunk shared across rows ----
    int id = bid - 96;                 // 0..2047
    int chunk = id & 31, g = id >> 5;  // chunk 0..31, row-group 0..63
    const float4* h4 = (const float4*)hid;
    const float4* w4 = (const float4*)vw_w;
    int cbase = chunk*1024;            // float4 units within the 32768-float4 flat hid
    float4 hv[4];
    #pragma unroll
    for (int k = 0; k < 4; ++k) hv[k] = h4[cbase + k*256 + t];
    float acc[4];
    #pragma unroll
    for (int r = 0; r < 4; ++r){
        long rb = (long)(g*4+r)*32768 + cbase;
        float4 a = {0,0,0,0};
        #pragma unroll
        for (int k = 0; k < 4; ++k) fma4(a, hv[k], w4[rb + k*256 + t]);
        acc[r] = hsum(a);
    }
    // per-thread partials, coalesced stores; reduced later in k_soft_vred
    #pragma unroll
    for (int r = 0; r < 4; ++r)
        partial[(g*4+r)*8192 + chunk*256 + t] = acc[r];
}

// ---------------- K4: blocks 0..127 row-softmax on S | blocks 128..383 value-row reduce ----------------
__global__ __launch_bounds__(256, 2) void k_soft_vred(float* __restrict__ S,
        const float* __restrict__ partial, const float* __restrict__ vb,
        const float* __restrict__ v3w, float* __restrict__ vred){
    int t = threadIdx.x;
    if (blockIdx.x >= 128){
        // reduce 8192 per-thread partials of row o; vred[o] = relu(sum+vb)*v3w
        int o = blockIdx.x - 128;
        const float4* p4 = (const float4*)(partial + o*8192);
        float4 a = {0,0,0,0};
        #pragma unroll
        for (int k = 0; k < 8; ++k){
            float4 v = p4[k*256 + t];
            a.x += v.x; a.y += v.y; a.z += v.z; a.w += v.w;
        }
        float s = hsum(a);
        for (int off = 32; off; off >>= 1) s += __shfl_xor(s, off);
        __shared__ float red[4];
        int lane = t & 63, wid = t >> 6;
        if (lane == 0) red[wid] = s;
        __syncthreads();
        if (t == 0){
            float tot = red[0]+red[1]+red[2]+red[3];
            vred[o] = fmaxf(tot + vb[o], 0.f) * v3w[o];
        }
        return;
    }
    int w = t >> 6, ln = t & 63;
    float* row = S + (blockIdx.x*4 + w)*512;
    float v[8];
    float m = -1e30f;
    #pragma unroll
    for (int k = 0; k < 8; ++k){ v[k] = row[ln + k*64]; m = fmaxf(m, v[k]); }
    for (int off = 32; off; off >>= 1) m = fmaxf(m, __shfl_xor(m, off));
    float s = 0.f;
    #pragma unroll
    for (int k = 0; k < 8; ++k){ v[k] = expf(v[k] - m); s += v[k]; }
    for (int off = 32; off; off >>= 1) s += __shfl_xor(s, off);
    float inv = 1.f / s;
    #pragma unroll
    for (int k = 0; k < 8; ++k) row[ln + k*64] = v[k]*inv;
}

// ---------------- K5: h = P @ VW + ob, grid 32 (8 i-tiles x 4 d-tiles) ----------------
__global__ __launch_bounds__(256, 2) void k_h(const float* __restrict__ P,
        const float* __restrict__ VW, const float* __restrict__ ob,
        float* __restrict__ hout){
    __shared__ float As[32*68];
    __shared__ float Bs[32*68];
    int bid = blockIdx.x;
    int ti = bid >> 2, tj = bid & 3;
    int i0 = ti*64, d0 = tj*64;
    int t = threadIdx.x, tx = t & 15, ty = t >> 4;
    float4 acc[4] = {{0,0,0,0},{0,0,0,0},{0,0,0,0},{0,0,0,0}};
    for (int k0 = 0; k0 < 512; k0 += 32){
        __syncthreads();
        stage_rows(As, P, i0, 512, k0, t);               // P chunk (transposed)
        #pragma unroll
        for (int half = 0; half < 2; ++half){
            int idx = half*256 + t;
            int kkr = idx >> 4, c4 = idx & 15;
            *(float4*)(Bs + kkr*68 + c4*4) = *(const float4*)(VW + (k0+kkr)*256 + d0 + c4*4);
        }
        __syncthreads();
        tile_compute(As, Bs, tx, ty, acc);
    }
    float4 bb = *(const float4*)(ob + d0 + tx*4);
    #pragma unroll
    for (int r = 0; r < 4; ++r){
        float4 o;
        o.x = acc[r].x + bb.x; o.y = acc[r].y + bb.y;
        o.z = acc[r].z + bb.z; o.w = acc[r].w + bb.w;
        *(float4*)(hout + (i0+ty*4+r)*256 + d0 + tx*4) = o;
    }
}

// ---------------- K6: A/B projections (blocks 0..511) || value finish (block 512) ----------------
__global__ __launch_bounds__(256, 2) void k_ab_value(const float* __restrict__ hin,
        const float* __restrict__ w2, const float* __restrict__ b2,
        const float* __restrict__ vred, const float* __restrict__ v3b,
        float* __restrict__ A, float* __restrict__ B, float* __restrict__ value){
    int t = threadIdx.x;
    if (blockIdx.x == 512){
        float s = vred[t];
        for (int off = 32; off; off >>= 1) s += __shfl_xor(s, off);
        __shared__ float redv[4];
        int lane = t & 63, wid = t >> 6;
        if (lane == 0) redv[wid] = s;
        __syncthreads();
        if (t == 0) value[0] = redv[0]+redv[1]+redv[2]+redv[3] + v3b[0];
        return;
    }
    __shared__ float lin[8*HIDD];
    int id = blockIdx.x, at = id >> 3, ot = id & 7;
    const float4* in4 = (const float4*)(hin + at*8*HIDD);
    ((float4*)lin)[t]       = in4[t];
    ((float4*)lin)[t + 256] = in4[t + 256];
    __syncthreads();
    int ol = t & 63, g = t >> 6;
    int o2 = ot*64 + ol;                   // 0..511
    bool isA = o2 < HIDD;
    int o = isA ? o2 : o2 - HIDD;
    const float4* w4 = (const float4*)(w2 + o*512 + (isA ? 0 : HIDD));
    const float4* la = (const float4*)(lin + (g*2)*HIDD);
    const float4* lb = (const float4*)(lin + (g*2+1)*HIDD);
    float4 acc0 = {0,0,0,0}, acc1 = {0,0,0,0};
    #pragma unroll 8
    for (int c = 0; c < HIDD/4; ++c){
        float4 wv = w4[c];
        fma4(acc0, la[c], wv);
        fma4(acc1, lb[c], wv);
    }
    int a0 = at*8 + g*2;
    float* dst = isA ? A : B;
    float bb = isA ? b2[o] : 0.f;          // fold fc2_b into A
    dst[a0*HIDD + o]     = hsum(acc0) + bb;
    dst[(a0+1)*HIDD + o] = hsum(acc1) + bb;
}

// ---------------- K7: per-pair x=relu(A[i]+B[j]); out = [sigmoid(wd.x+bd), 1-., value] ----------------
__global__ __launch_bounds__(256, 2) void k_pairs(const float* __restrict__ A,
        const float* __restrict__ B, const float* __restrict__ w3,
        const float* __restrict__ b3, const float* __restrict__ value,
        float* __restrict__ out){
    int ti = blockIdx.x, tj = blockIdx.y;
    if (tj < ti) return;                   // strictly-lower tiles have no pairs
    __shared__ float la[16*260], lb[16*260], lw[256];
    int t = threadIdx.x;
    #pragma unroll
    for (int l = 0; l < 4; ++l){
        int idx = l*256 + t;
        int r = idx >> 6, c4 = idx & 63;
        ((float4*)la)[r*65 + c4] = ((const float4*)A)[(ti*16 + r)*64 + c4];
        ((float4*)lb)[r*65 + c4] = ((const float4*)B)[(tj*16 + r)*64 + c4];
    }
    lw[t] = w3[t] - w3[256 + t];           // fc3_w[0]-fc3_w[1]
    __syncthreads();
    float val = value[0];
    float bd  = b3[0] - b3[1];
    int il = t >> 4, jl = t & 15;
    int i = ti*16 + il, j = tj*16 + jl;
    if (j > i){
        const float4* a4 = (const float4*)(la + il*260);
        const float4* b4 = (const float4*)(lb + jl*260);
        const float4* w4 = (const float4*)lw;
        float4 acc = {0,0,0,0};
        #pragma unroll 8
        for (int c = 0; c < 64; ++c){
            float4 aa = a4[c], bb = b4[c], wv = w4[c];
            acc.x += fmaxf(aa.x + bb.x, 0.f)*wv.x;
            acc.y += fmaxf(aa.y + bb.y, 0.f)*wv.y;
            acc.z += fmaxf(aa.z + bb.z, 0.f)*wv.z;
            acc.w += fmaxf(aa.w + bb.w, 0.f)*wv.w;
        }
        float z = hsum(acc) + bd;
        float o0 = 1.f/(1.f + expf(-z));
        int p = i*511 - (i*(i-1))/2 + (j - i - 1);
        out[3*p]   = o0;
        out[3*p+1] = 1.f - o0;
        out[3*p+2] = val;
    }
}

extern "C" void kernel_launch(void* const* d_in, const int* in_sizes, int n_in,
                              void* d_out, int out_size, void* d_ws, size_t ws_size,
                              hipStream_t stream){
    const float* inputs = (const float*)d_in[0];
    const float* fc1_w  = (const float*)d_in[1];
    const float* fc1_b  = (const float*)d_in[2];
    const float* inp_w  = (const float*)d_in[3];
    const float* inp_b  = (const float*)d_in[4];
    const float* outp_w = (const float*)d_in[5];
    const float* outp_b = (const float*)d_in[6];
    const float* fc2_w  = (const float*)d_in[7];
    const float* fc2_b  = (const float*)d_in[8];
    const float* fc3_w  = (const float*)d_in[9];
    const float* fc3_b  = (const float*)d_in[10];
    const float* vfc2_w = (const float*)d_in[11];
    const float* vfc2_b = (const float*)d_in[12];
    const float* vfc3_w = (const float*)d_in[13];
    const float* vfc3_b = (const float*)d_in[14];
    float* out = (float*)d_out;
    float* ws  = (float*)d_ws;
    // ws layout (floats)
    float* hid     = ws;              // 512*256   = 131072
    float* qkv     = ws + 131072;     // 512*768   = 393216
    float* S       = ws + 524288;     // 512*512   = 262144  (scores -> softmax in place)
    float* VW      = ws + 786432;     // 512*256   = 131072
    float* h       = ws + 917504;     // 512*256   = 131072
    float* A       = ws + 1048576;    // 512*256   = 131072
    float* B       = ws + 1179648;    // 512*256   = 131072
    float* partial = ws + 1310720;    // 256*8192  = 2097152 (8 MB per-thread partials)
    float* vred    = ws + 3407872;    // 256
    float* value   = ws + 3408128;    // 1

    k_fc1      <<<dim3(4, 64),  256, 0, stream>>>(inputs, fc1_w, fc1_b, hid);
    k_qkv      <<<dim3(12, 64), 256, 0, stream>>>(hid, inp_w, inp_b, qkv);
    k_big      <<<dim3(2144),   256, 0, stream>>>(qkv, outp_w, hid, vfc2_w, S, VW, partial);
    k_soft_vred<<<dim3(384),    256, 0, stream>>>(S, partial, vfc2_b, vfc3_w, vred);
    k_h        <<<dim3(32),     256, 0, stream>>>(S, VW, outp_b, h);
    k_ab_value <<<dim3(513),    256, 0, stream>>>(h, fc2_w, fc2_b, vred, vfc3_b, A, B, value);
    k_pairs    <<<dim3(32, 32), 256, 0, stream>>>(A, B, fc3_w, fc3_b, value, out);
}